// Round 10
// baseline (76.107 us; speedup 1.0000x reference)
//
#include <hip/hip_runtime.h>
#include <math.h>

#define BATCH 32
#define H 512
#define W 512
#define PAD 15
#define R 4                         /* output rows per wave */
#define BANDS (H / R)               /* 128 */
#define NWAVES (BATCH * BANDS)      /* 4096 */
#define WPB 4                       /* waves per block */
#define NBLOCKS (NWAVES / WPB)      /* 1024 */
#define NXCD 8
#define INV_KK (1.0f / 961.0f)

/* Per-row fused weight+BCE using the segment-sum horizontal window.
   All locals constant-indexed -> SROA-safe. (verified R2..R8, absmax 0) */
#define ROW_BODY(va, vb, yy)                                                  \
    {                                                                         \
        const float4* tp_ = (const float4*)(tb + (size_t)(yy) * W + x0);      \
        const float4* lp_ = (const float4*)(lb + (size_t)(yy) * W + x0);      \
        float4 t0_ = tp_[0], t1_ = tp_[1];                                    \
        float4 l0_ = lp_[0], l1_ = lp_[1];                                    \
        float p_[8];                                                          \
        p_[0] = (va).x;          p_[1] = p_[0] + (va).y;                      \
        p_[2] = p_[1] + (va).z;  p_[3] = p_[2] + (va).w;                      \
        p_[4] = p_[3] + (vb).x;  p_[5] = p_[4] + (vb).y;                      \
        p_[6] = p_[5] + (vb).z;  p_[7] = p_[6] + (vb).w;                      \
        const float tot_ = p_[7];                                             \
        float pm2_[8], pe_[7];                                                \
        _Pragma("unroll")                                                     \
        for (int k = 0; k < 8; ++k) pm2_[k] = __shfl_up(p_[k], 2);            \
        _Pragma("unroll")                                                     \
        for (int k = 0; k < 7; ++k) pe_[k] = __shfl_down(p_[k], 2);           \
        const float bm_ = __shfl_up(tot_, 1);                                 \
        const float dp_ = __shfl_down(tot_, 1);                               \
        const float base_ = (okm1 ? bm_ : 0.f) + tot_ + (okp1 ? dp_ : 0.f);   \
        float tv_[8] = {t0_.x, t0_.y, t0_.z, t0_.w, t1_.x, t1_.y, t1_.z, t1_.w}; \
        float lv_[8] = {l0_.x, l0_.y, l0_.z, l0_.w, l1_.x, l1_.y, l1_.z, l1_.w}; \
        _Pragma("unroll")                                                     \
        for (int k = 0; k < 8; ++k) {                                         \
            float aa_ = okm2 ? (pm2_[7] - pm2_[k]) : 0.f;                     \
            float ee_ = (k >= 1 && okp2) ? pe_[k - 1] : 0.f;                  \
            float hs_ = aa_ + base_ + ee_;                                    \
            float pooled_ = hs_ * INV_KK;                                     \
            float wgt_ = fmaf(5.f, fabsf(pooled_ - tv_[k]), 1.f);             \
            float al_ = fabsf(lv_[k]);                                        \
            float bce_ = fmaxf(lv_[k], 0.f) - lv_[k] * tv_[k]                 \
                         + __logf(1.f + __expf(-al_));                        \
            num = fmaf(wgt_, bce_, num);                                      \
            den += wgt_;                                                      \
        }                                                                     \
    }

#define LOAD_FAST(ra, rb, y)                                                  \
    { const float4* p_ = (const float4*)(tb + (size_t)(y) * W + x0);          \
      ra = p_[0]; rb = p_[1]; }

#define LOAD_SAFE(ra, rb, y)                                                  \
    { ra = make_float4(0.f, 0.f, 0.f, 0.f); rb = ra;                          \
      if ((unsigned)(y) < (unsigned)H) {                                      \
          const float4* p_ = (const float4*)(tb + (size_t)(y) * W + x0);      \
          ra = p_[0]; rb = p_[1]; } }

/* sum rows y0-15 .. y0+15 into (va_, vb_); chunked so bounded loads in flight */
#define CHUNKV(LOADER, C0, C1)                                                \
    _Pragma("unroll")                                                         \
    for (int c = (C0); c < (C1); ++c) {                                       \
        const int y = y0 + c - PAD;                                           \
        float4 ra, rb;                                                        \
        LOADER(ra, rb, y)                                                     \
        va_ += ra; vb_ += rb;                                                 \
    }

#define STREAM31(LOADER)                                                      \
    CHUNKV(LOADER, 0, 6)   __builtin_amdgcn_sched_barrier(0);                 \
    CHUNKV(LOADER, 6, 12)  __builtin_amdgcn_sched_barrier(0);                 \
    CHUNKV(LOADER, 12, 18) __builtin_amdgcn_sched_barrier(0);                 \
    CHUNKV(LOADER, 18, 24) __builtin_amdgcn_sched_barrier(0);                 \
    CHUNKV(LOADER, 24, 31)

/* slide + ROW_BODY sequence; prefetch enter/leave rows before the math that
   hides their latency */
#define PHASE_B(LOADER)                                                       \
    {                                                                         \
        float4 e0a, e0b, l0a, l0b;                                            \
        LOADER(e0a, e0b, y0 + 16) LOADER(l0a, l0b, y0 - 15)                   \
        ROW_BODY(va_, vb_, y0 + 0)                                            \
        va_ += e0a - l0a; vb_ += e0b - l0b;                                   \
        float4 e1a, e1b, l1a, l1b;                                            \
        LOADER(e1a, e1b, y0 + 17) LOADER(l1a, l1b, y0 - 14)                   \
        ROW_BODY(va_, vb_, y0 + 1)                                            \
        va_ += e1a - l1a; vb_ += e1b - l1b;                                   \
        float4 e2a, e2b, l2a, l2b;                                            \
        LOADER(e2a, e2b, y0 + 18) LOADER(l2a, l2b, y0 - 13)                   \
        ROW_BODY(va_, vb_, y0 + 2)                                            \
        va_ += e2a - l2a; vb_ += e2b - l2b;                                   \
        ROW_BODY(va_, vb_, y0 + 3)                                            \
    }

__global__ __launch_bounds__(WPB * 64)
__attribute__((amdgpu_waves_per_eu(4)))
void wbce_wave_kernel(const float* __restrict__ logits,
                      const float* __restrict__ targets,
                      float* __restrict__ partials) {
    __shared__ float rn[WPB], rd[WPB];

    const int tid  = threadIdx.x;
    const int lane = tid & 63;
    const int w    = tid >> 6;

    /* XCD-aware bijective swizzle: 128 consecutive blocks (4 images) per XCD
       so vertically-adjacent blocks (30 shared halo rows) share an L2 */
    const int bid  = (int)blockIdx.x;
    const int sbid = (bid & (NXCD - 1)) * (NBLOCKS / NXCD) + (bid >> 3);

    const int wid  = sbid * WPB + w;
    const int img  = wid >> 7;            /* wid / BANDS */
    const int band = wid & (BANDS - 1);
    const int y0   = band * R;
    const int x0   = lane * 8;

    const float* tb = targets + (size_t)img * H * W;
    const float* lb = logits  + (size_t)img * H * W;

    const bool okm2 = lane >= 2, okm1 = lane >= 1;
    const bool okp1 = lane <= 62, okp2 = lane <= 61;
    float num = 0.f, den = 0.f;

    float4 va_ = {0, 0, 0, 0}, vb_ = {0, 0, 0, 0};

    if (y0 >= PAD && y0 + 19 <= H) {      /* interior band: no bounds checks */
        STREAM31(LOAD_FAST)
        PHASE_B(LOAD_FAST)
    } else {
        STREAM31(LOAD_SAFE)
        PHASE_B(LOAD_SAFE)
    }

    /* ---- wave + block reduction, one partial pair per block ---- */
    #pragma unroll
    for (int off = 32; off > 0; off >>= 1) {
        num += __shfl_down(num, off);
        den += __shfl_down(den, off);
    }
    if (lane == 0) { rn[w] = num; rd[w] = den; }
    __syncthreads();
    if (tid == 0) {
        float n = 0.f, d = 0.f;
        #pragma unroll
        for (int i = 0; i < WPB; ++i) { n += rn[i]; d += rd[i]; }
        partials[sbid * 2]     = n;
        partials[sbid * 2 + 1] = d;
    }
}

/* 1024 partial pairs -> scalar. Image i owns pairs [i*32, i*32+32). */
__global__ __launch_bounds__(1024)
void wbce_finalize_kernel(const float* __restrict__ partials,
                          float* __restrict__ out) {
    __shared__ float rsum[16];
    const int t = threadIdx.x;
    float num = partials[t * 2];
    float den = partials[t * 2 + 1];
    #pragma unroll
    for (int off = 16; off > 0; off >>= 1) {
        num += __shfl_down(num, off, 32);
        den += __shfl_down(den, off, 32);
    }
    float ratio = 0.f;
    if ((t & 31) == 0) ratio = num / den;
    ratio += __shfl_down(ratio, 32);          /* lane0 += lane32 */
    const int lane = t & 63;
    const int wv = t >> 6;
    if (lane == 0) rsum[wv] = ratio;
    __syncthreads();
    if (t == 0) {
        float s = 0.f;
        #pragma unroll
        for (int i = 0; i < 16; ++i) s += rsum[i];
        out[0] = s / (float)BATCH;
    }
}

extern "C" void kernel_launch(void* const* d_in, const int* in_sizes, int n_in,
                              void* d_out, int out_size, void* d_ws, size_t ws_size,
                              hipStream_t stream) {
    const float* logits  = (const float*)d_in[0];
    const float* targets = (const float*)d_in[1];
    float* out = (float*)d_out;
    float* partials = (float*)d_ws;   /* NBLOCKS*2 floats = 8 KB */

    wbce_wave_kernel<<<NBLOCKS, WPB * 64, 0, stream>>>(logits, targets, partials);
    wbce_finalize_kernel<<<1, 1024, 0, stream>>>(partials, out);
}

// Round 11
// 27.312 us; speedup vs baseline: 2.7866x; 2.7866x over previous
//
#include <hip/hip_runtime.h>
#include <math.h>

#define BATCH 32
#define H 512
#define W 512
#define PAD 15
#define BAND 16                       /* rows per block */
#define NBANDS (H / BAND)             /* 32 */
#define NBLOCKS (BATCH * NBANDS)      /* 1024 */
#define NXCD 8
#define INV_KK (1.0f / 961.0f)

/* ---------- fused weight + stable BCE for one element (verified R8) ------ */
#define EMIT(tv, lv, hs)                                                      \
    {                                                                         \
        float pooled_ = (hs) * INV_KK;                                        \
        float wgt_ = fmaf(5.f, fabsf(pooled_ - (tv)), 1.f);                   \
        float al_ = fabsf(lv);                                                \
        float bce_ = fmaxf((lv), 0.f) - (lv) * (tv)                           \
                     + __logf(1.f + __expf(-al_));                            \
        num = fmaf(wgt_, bce_, num);                                          \
        den += wgt_;                                                          \
    }

/* one k-slot of the horizontal 31-window (verified bit-exact R7/R8) */
#define KSLOT(pk, pkm1, tv, lv, FIRST, LAST)                                  \
    {                                                                         \
        float hs_ = base_;                                                    \
        if (!(LAST)) {                                                        \
            float sa_ = __shfl_up(tot_ - (pk), 2);                            \
            hs_ += okm2 ? sa_ : 0.f;                                          \
        }                                                                     \
        if (!(FIRST)) {                                                       \
            float se_ = __shfl_down((pkm1), 2);                               \
            hs_ += okp2 ? se_ : 0.f;                                          \
        }                                                                     \
        EMIT(tv, lv, hs_)                                                     \
    }

#define ROW_EMIT(va, vb, t0_, t1_, l0_, l1_)                                  \
    {                                                                         \
        const float p0_ = (va).x;                                             \
        const float p1_ = p0_ + (va).y;                                       \
        const float p2_ = p1_ + (va).z;                                       \
        const float p3_ = p2_ + (va).w;                                       \
        const float p4_ = p3_ + (vb).x;                                       \
        const float p5_ = p4_ + (vb).y;                                       \
        const float p6_ = p5_ + (vb).z;                                       \
        const float tot_ = p6_ + (vb).w;                                      \
        const float bm_ = __shfl_up(tot_, 1);                                 \
        const float dp_ = __shfl_down(tot_, 1);                               \
        const float base_ = (okm1 ? bm_ : 0.f) + tot_ + (okp1 ? dp_ : 0.f);   \
        KSLOT(p0_, 0.f, (t0_).x, (l0_).x, 1, 0)                               \
        KSLOT(p1_, p0_, (t0_).y, (l0_).y, 0, 0)                               \
        KSLOT(p2_, p1_, (t0_).z, (l0_).z, 0, 0)                               \
        KSLOT(p3_, p2_, (t0_).w, (l0_).w, 0, 0)                               \
        KSLOT(p4_, p3_, (t1_).x, (l1_).x, 0, 0)                               \
        KSLOT(p5_, p4_, (t1_).y, (l1_).y, 0, 0)                               \
        KSLOT(p6_, p5_, (t1_).z, (l1_).z, 0, 0)                               \
        KSLOT(0.f, p6_, (t1_).w, (l1_).w, 0, 1)                               \
    }

#define LDG(pa, pb, ptr, yy)                                                  \
    { const float4* p_ = (const float4*)((ptr) + (size_t)(yy) * W + x0);      \
      pa = p_[0]; pb = p_[1]; }

/* ---------- Phase 1: vertical running windows into LDS ------------------ */
/* thread owns columns tid and tid+256; G=1 -> interior band, no guards     */
#define P1_INIT(G, C0, C1)                                                    \
    _Pragma("unroll")                                                         \
    for (int c = (C0); c < (C1); ++c) {                                       \
        const int y = y0 + c - PAD;                                           \
        float a0 = 0.f, a1 = 0.f;                                             \
        if ((G) || (unsigned)y < (unsigned)H) {                               \
            a0 = tcol[y * W]; a1 = tcol[y * W + 256];                         \
        }                                                                     \
        run0 += a0; run1 += a1;                                               \
    }

#define P1_SLIDE(G, J0, J1)                                                   \
    _Pragma("unroll")                                                         \
    for (int j = (J0); j < (J1); ++j) {                                       \
        vs[j][tid] = run0; vs[j][tid + 256] = run1;                           \
        if (j < BAND - 1) {                                                   \
            const int ye = y0 + j + PAD + 1, yl = y0 + j - PAD;               \
            float e0 = 0.f, e1 = 0.f, s0 = 0.f, s1 = 0.f;                     \
            if ((G) || (unsigned)ye < (unsigned)H) {                          \
                e0 = tcol[ye * W]; e1 = tcol[ye * W + 256];                   \
            }                                                                 \
            if ((G) || (unsigned)yl < (unsigned)H) {                          \
                s0 = tcol[yl * W]; s1 = tcol[yl * W + 256];                   \
            }                                                                 \
            run0 += e0 - s0; run1 += e1 - s1;                                 \
        }                                                                     \
    }

#define PHASE1(G)                                                             \
    P1_INIT(G, 0, 8)   __builtin_amdgcn_sched_barrier(0);                     \
    P1_INIT(G, 8, 16)  __builtin_amdgcn_sched_barrier(0);                     \
    P1_INIT(G, 16, 24) __builtin_amdgcn_sched_barrier(0);                     \
    P1_INIT(G, 24, 31)                                                        \
    P1_SLIDE(G, 0, 4)  __builtin_amdgcn_sched_barrier(0);                     \
    P1_SLIDE(G, 4, 8)  __builtin_amdgcn_sched_barrier(0);                     \
    P1_SLIDE(G, 8, 12) __builtin_amdgcn_sched_barrier(0);                     \
    P1_SLIDE(G, 12, 16)

__global__ __launch_bounds__(256)
void wbce_band_kernel(const float* __restrict__ logits,
                      const float* __restrict__ targets,
                      float* __restrict__ partials) {
    __shared__ __align__(16) float vs[BAND][W];   /* 32 KB */
    __shared__ float rn[4], rd[4];

    const int tid  = threadIdx.x;
    const int lane = tid & 63;
    const int w    = tid >> 6;

    /* XCD-aware bijective swizzle: 128 consecutive blocks (4 images) per XCD */
    const int bid  = (int)blockIdx.x;
    const int sbid = (bid & (NXCD - 1)) * (NBLOCKS / NXCD) + (bid >> 3);

    const int img  = sbid >> 5;            /* sbid / NBANDS */
    const int band = sbid & (NBANDS - 1);
    const int y0   = band * BAND;
    const int x0   = lane * 8;

    const float* tb = targets + (size_t)img * H * W;
    const float* lb = logits  + (size_t)img * H * W;
    const float* tcol = tb + tid;

    /* ---- Phase 1: cooperative vertical 31-row windows -> LDS ---- */
    float run0 = 0.f, run1 = 0.f;
    if (y0 >= PAD && y0 + BAND + PAD - 1 < H) {
        PHASE1(1)
    } else {
        PHASE1(0)
    }
    __syncthreads();

    /* ---- Phase 2: horizontal window + fused weight/BCE (wave = 4 rows) ---- */
    const bool okm2 = lane >= 2, okm1 = lane >= 1;
    const bool okp1 = lane <= 62, okp2 = lane <= 61;
    float num = 0.f, den = 0.f;

    const int jw = w * 4;
    {
        float4 A0 = ((const float4*)vs[jw + 0])[2 * lane];
        float4 B0 = ((const float4*)vs[jw + 0])[2 * lane + 1];
        float4 A1 = ((const float4*)vs[jw + 1])[2 * lane];
        float4 B1 = ((const float4*)vs[jw + 1])[2 * lane + 1];
        float4 T0a, T0b, T1a, T1b, L0a, L0b, L1a, L1b;
        LDG(T0a, T0b, tb, y0 + jw + 0) LDG(L0a, L0b, lb, y0 + jw + 0)
        LDG(T1a, T1b, tb, y0 + jw + 1) LDG(L1a, L1b, lb, y0 + jw + 1)
        ROW_EMIT(A0, B0, T0a, T0b, L0a, L0b)
        ROW_EMIT(A1, B1, T1a, T1b, L1a, L1b)
    }
    __builtin_amdgcn_sched_barrier(0);
    {
        float4 A2 = ((const float4*)vs[jw + 2])[2 * lane];
        float4 B2 = ((const float4*)vs[jw + 2])[2 * lane + 1];
        float4 A3 = ((const float4*)vs[jw + 3])[2 * lane];
        float4 B3 = ((const float4*)vs[jw + 3])[2 * lane + 1];
        float4 T2a, T2b, T3a, T3b, L2a, L2b, L3a, L3b;
        LDG(T2a, T2b, tb, y0 + jw + 2) LDG(L2a, L2b, lb, y0 + jw + 2)
        LDG(T3a, T3b, tb, y0 + jw + 3) LDG(L3a, L3b, lb, y0 + jw + 3)
        ROW_EMIT(A2, B2, T2a, T2b, L2a, L2b)
        ROW_EMIT(A3, B3, T3a, T3b, L3a, L3b)
    }

    /* ---- wave + block reduction, one partial pair per block ---- */
    #pragma unroll
    for (int off = 32; off > 0; off >>= 1) {
        num += __shfl_down(num, off);
        den += __shfl_down(den, off);
    }
    if (lane == 0) { rn[w] = num; rd[w] = den; }
    __syncthreads();
    if (tid == 0) {
        float n = 0.f, d = 0.f;
        #pragma unroll
        for (int i = 0; i < 4; ++i) { n += rn[i]; d += rd[i]; }
        partials[sbid * 2]     = n;
        partials[sbid * 2 + 1] = d;
    }
}

/* 1024 partial pairs -> scalar. Image i owns pairs [i*32, i*32+32). */
__global__ __launch_bounds__(1024)
void wbce_finalize_kernel(const float* __restrict__ partials,
                          float* __restrict__ out) {
    __shared__ float rsum[16];
    const int t = threadIdx.x;
    float num = partials[t * 2];
    float den = partials[t * 2 + 1];
    #pragma unroll
    for (int off = 16; off > 0; off >>= 1) {
        num += __shfl_down(num, off, 32);
        den += __shfl_down(den, off, 32);
    }
    float ratio = 0.f;
    if ((t & 31) == 0) ratio = num / den;
    ratio += __shfl_down(ratio, 32);          /* lane0 += lane32 */
    const int lane = t & 63;
    const int wv = t >> 6;
    if (lane == 0) rsum[wv] = ratio;
    __syncthreads();
    if (t == 0) {
        float s = 0.f;
        #pragma unroll
        for (int i = 0; i < 16; ++i) s += rsum[i];
        out[0] = s / (float)BATCH;
    }
}

extern "C" void kernel_launch(void* const* d_in, const int* in_sizes, int n_in,
                              void* d_out, int out_size, void* d_ws, size_t ws_size,
                              hipStream_t stream) {
    const float* logits  = (const float*)d_in[0];
    const float* targets = (const float*)d_in[1];
    float* out = (float*)d_out;
    float* partials = (float*)d_ws;   /* NBLOCKS*2 floats = 8 KB */

    wbce_band_kernel<<<NBLOCKS, 256, 0, stream>>>(logits, targets, partials);
    wbce_finalize_kernel<<<1, 1024, 0, stream>>>(partials, out);
}

// Round 12
// 25.291 us; speedup vs baseline: 3.0092x; 1.0799x over previous
//
#include <hip/hip_runtime.h>
#include <math.h>

#define BATCH 32
#define H 512
#define W 512
#define PAD 15
#define BAND 8                        /* rows per block */
#define NBANDS (H / BAND)             /* 64 */
#define NBLOCKS (BATCH * NBANDS)      /* 2048 */
#define NXCD 8
#define INV_KK (1.0f / 961.0f)

/* ---------- fused weight + stable BCE for one element (verified R8) ------ */
#define EMIT(tv, lv, hs)                                                      \
    {                                                                         \
        float pooled_ = (hs) * INV_KK;                                        \
        float wgt_ = fmaf(5.f, fabsf(pooled_ - (tv)), 1.f);                   \
        float al_ = fabsf(lv);                                                \
        float bce_ = fmaxf((lv), 0.f) - (lv) * (tv)                           \
                     + __logf(1.f + __expf(-al_));                            \
        num = fmaf(wgt_, bce_, num);                                          \
        den += wgt_;                                                          \
    }

/* one k-slot of the horizontal 31-window (verified bit-exact R7..R11) */
#define KSLOT(pk, pkm1, tv, lv, FIRST, LAST)                                  \
    {                                                                         \
        float hs_ = base_;                                                    \
        if (!(LAST)) {                                                        \
            float sa_ = __shfl_up(tot_ - (pk), 2);                            \
            hs_ += okm2 ? sa_ : 0.f;                                          \
        }                                                                     \
        if (!(FIRST)) {                                                       \
            float se_ = __shfl_down((pkm1), 2);                               \
            hs_ += okp2 ? se_ : 0.f;                                          \
        }                                                                     \
        EMIT(tv, lv, hs_)                                                     \
    }

#define ROW_EMIT(va, vb, t0_, t1_, l0_, l1_)                                  \
    {                                                                         \
        const float p0_ = (va).x;                                             \
        const float p1_ = p0_ + (va).y;                                       \
        const float p2_ = p1_ + (va).z;                                       \
        const float p3_ = p2_ + (va).w;                                       \
        const float p4_ = p3_ + (vb).x;                                       \
        const float p5_ = p4_ + (vb).y;                                       \
        const float p6_ = p5_ + (vb).z;                                       \
        const float tot_ = p6_ + (vb).w;                                      \
        const float bm_ = __shfl_up(tot_, 1);                                 \
        const float dp_ = __shfl_down(tot_, 1);                               \
        const float base_ = (okm1 ? bm_ : 0.f) + tot_ + (okp1 ? dp_ : 0.f);   \
        KSLOT(p0_, 0.f, (t0_).x, (l0_).x, 1, 0)                               \
        KSLOT(p1_, p0_, (t0_).y, (l0_).y, 0, 0)                               \
        KSLOT(p2_, p1_, (t0_).z, (l0_).z, 0, 0)                               \
        KSLOT(p3_, p2_, (t0_).w, (l0_).w, 0, 0)                               \
        KSLOT(p4_, p3_, (t1_).x, (l1_).x, 0, 0)                               \
        KSLOT(p5_, p4_, (t1_).y, (l1_).y, 0, 0)                               \
        KSLOT(p6_, p5_, (t1_).z, (l1_).z, 0, 0)                               \
        KSLOT(0.f, p6_, (t1_).w, (l1_).w, 0, 1)                               \
    }

#define LDG(pa, pb, ptr, yy)                                                  \
    { const float4* p_ = (const float4*)((ptr) + (size_t)(yy) * W + x0);      \
      pa = p_[0]; pb = p_[1]; }

/* ---------- Phase 1: vertical running windows into LDS ------------------ */
/* thread owns columns tid and tid+256; G=1 -> interior band, no guards     */
#define P1_INIT(G, C0, C1)                                                    \
    _Pragma("unroll")                                                         \
    for (int c = (C0); c < (C1); ++c) {                                       \
        const int y = y0 + c - PAD;                                           \
        float a0 = 0.f, a1 = 0.f;                                             \
        if ((G) || (unsigned)y < (unsigned)H) {                               \
            a0 = tcol[y * W]; a1 = tcol[y * W + 256];                         \
        }                                                                     \
        run0 += a0; run1 += a1;                                               \
    }

#define P1_SLIDE(G, J0, J1)                                                   \
    _Pragma("unroll")                                                         \
    for (int j = (J0); j < (J1); ++j) {                                       \
        vs[j][tid] = run0; vs[j][tid + 256] = run1;                           \
        if (j < BAND - 1) {                                                   \
            const int ye = y0 + j + PAD + 1, yl = y0 + j - PAD;               \
            float e0 = 0.f, e1 = 0.f, s0 = 0.f, s1 = 0.f;                     \
            if ((G) || (unsigned)ye < (unsigned)H) {                          \
                e0 = tcol[ye * W]; e1 = tcol[ye * W + 256];                   \
            }                                                                 \
            if ((G) || (unsigned)yl < (unsigned)H) {                          \
                s0 = tcol[yl * W]; s1 = tcol[yl * W + 256];                   \
            }                                                                 \
            run0 += e0 - s0; run1 += e1 - s1;                                 \
        }                                                                     \
    }

#define PHASE1(G)                                                             \
    P1_INIT(G, 0, 8)   __builtin_amdgcn_sched_barrier(0);                     \
    P1_INIT(G, 8, 16)  __builtin_amdgcn_sched_barrier(0);                     \
    P1_INIT(G, 16, 24) __builtin_amdgcn_sched_barrier(0);                     \
    P1_INIT(G, 24, 31)                                                        \
    P1_SLIDE(G, 0, 4)  __builtin_amdgcn_sched_barrier(0);                     \
    P1_SLIDE(G, 4, 8)

__global__ __launch_bounds__(256)
void wbce_band_kernel(const float* __restrict__ logits,
                      const float* __restrict__ targets,
                      float* __restrict__ partials) {
    __shared__ __align__(16) float vs[BAND][W];   /* 16 KB */
    __shared__ float rn[4], rd[4];

    const int tid  = threadIdx.x;
    const int lane = tid & 63;
    const int w    = tid >> 6;

    /* XCD-aware bijective swizzle: 256 consecutive blocks (4 images) per XCD */
    const int bid  = (int)blockIdx.x;
    const int sbid = (bid & (NXCD - 1)) * (NBLOCKS / NXCD) + (bid >> 3);

    const int img  = sbid >> 6;            /* sbid / NBANDS */
    const int band = sbid & (NBANDS - 1);
    const int y0   = band * BAND;
    const int x0   = lane * 8;

    const float* tb = targets + (size_t)img * H * W;
    const float* lb = logits  + (size_t)img * H * W;
    const float* tcol = tb + tid;

    /* ---- Phase 2 prefetch (independent of Phase 1): wave = 2 rows ---- */
    const int jw = w * 2;
    float4 T0a, T0b, T1a, T1b, L0a, L0b, L1a, L1b;
    LDG(T0a, T0b, tb, y0 + jw + 0) LDG(L0a, L0b, lb, y0 + jw + 0)
    LDG(T1a, T1b, tb, y0 + jw + 1) LDG(L1a, L1b, lb, y0 + jw + 1)
    __builtin_amdgcn_sched_barrier(0);

    /* ---- Phase 1: cooperative vertical 31-row windows -> LDS ---- */
    float run0 = 0.f, run1 = 0.f;
    if (y0 >= PAD && y0 + BAND + PAD - 1 < H) {
        PHASE1(1)
    } else {
        PHASE1(0)
    }
    __syncthreads();

    /* ---- Phase 2: horizontal window + fused weight/BCE ---- */
    const bool okm2 = lane >= 2, okm1 = lane >= 1;
    const bool okp1 = lane <= 62, okp2 = lane <= 61;
    float num = 0.f, den = 0.f;

    {
        float4 A0 = ((const float4*)vs[jw + 0])[2 * lane];
        float4 B0 = ((const float4*)vs[jw + 0])[2 * lane + 1];
        float4 A1 = ((const float4*)vs[jw + 1])[2 * lane];
        float4 B1 = ((const float4*)vs[jw + 1])[2 * lane + 1];
        ROW_EMIT(A0, B0, T0a, T0b, L0a, L0b)
        ROW_EMIT(A1, B1, T1a, T1b, L1a, L1b)
    }

    /* ---- wave + block reduction, one partial pair per block ---- */
    #pragma unroll
    for (int off = 32; off > 0; off >>= 1) {
        num += __shfl_down(num, off);
        den += __shfl_down(den, off);
    }
    if (lane == 0) { rn[w] = num; rd[w] = den; }
    __syncthreads();
    if (tid == 0) {
        float n = 0.f, d = 0.f;
        #pragma unroll
        for (int i = 0; i < 4; ++i) { n += rn[i]; d += rd[i]; }
        partials[sbid * 2]     = n;
        partials[sbid * 2 + 1] = d;
    }
}

/* 2048 partial pairs -> scalar. Image i owns pairs [i*64, i*64+64). */
__global__ __launch_bounds__(1024)
void wbce_finalize_kernel(const float* __restrict__ partials,
                          float* __restrict__ out) {
    __shared__ float rsum[16];
    const int t = threadIdx.x;
    const int img = t >> 5;
    const int j = t & 31;
    const int base = img * NBANDS;
    float num = partials[(base + j) * 2]     + partials[(base + 32 + j) * 2];
    float den = partials[(base + j) * 2 + 1] + partials[(base + 32 + j) * 2 + 1];
    #pragma unroll
    for (int off = 16; off > 0; off >>= 1) {
        num += __shfl_down(num, off, 32);
        den += __shfl_down(den, off, 32);
    }
    float ratio = 0.f;
    if ((t & 31) == 0) ratio = num / den;
    ratio += __shfl_down(ratio, 32);          /* lane0 += lane32 */
    const int lane = t & 63;
    const int wv = t >> 6;
    if (lane == 0) rsum[wv] = ratio;
    __syncthreads();
    if (t == 0) {
        float s = 0.f;
        #pragma unroll
        for (int i = 0; i < 16; ++i) s += rsum[i];
        out[0] = s / (float)BATCH;
    }
}

extern "C" void kernel_launch(void* const* d_in, const int* in_sizes, int n_in,
                              void* d_out, int out_size, void* d_ws, size_t ws_size,
                              hipStream_t stream) {
    const float* logits  = (const float*)d_in[0];
    const float* targets = (const float*)d_in[1];
    float* out = (float*)d_out;
    float* partials = (float*)d_ws;   /* NBLOCKS*2 floats = 16 KB */

    wbce_band_kernel<<<NBLOCKS, 256, 0, stream>>>(logits, targets, partials);
    wbce_finalize_kernel<<<1, 1024, 0, stream>>>(partials, out);
}